// Round 14
// baseline (638.481 us; speedup 1.0000x reference)
//
#include <hip/hip_runtime.h>

// FirNeXtV2 DDSP synth, optimized round 1.
// Numerics (certified r13): chunked f32 cumsum (base 16, sequential within
// chunk, recursive carries, one rounded add per level), f32 Dirichlet eval
// (ocml sinf, numpy op order), f32 convs. All add sequences preserved bitwise.
// Perf: register-blocked FIRs (R=4 outputs/thread, sliding coeff window,
// wave-uniform hk loads, skewed-LDS sources), parallelized scan, fused carry.

#define BLKS  512
#define WL    2048
#define W4    512
#define NB    4
#define NFR   512
#define LTOT  (NFR*BLKS)     // 262144
#define NCH   (LTOT/16)      // 16384 level-1 length
#define SN_LEN 260096        // WL*127
#define SK(u) ((u) + ((u) >> 5))   // LDS bank skew

// ---------------------------------------------------------------------------
// Scan stage A: level-0 chunk scans. d is recomputed from f0 (16 | 512 so a
// 16-chunk never crosses a frame boundary -> single d per chunk, no loads).
// Bitwise: acc = RN(acc + d) sixteen times, as in the r13 scan.
// ---------------------------------------------------------------------------
__global__ void __launch_bounds__(256) k_scan_a(const float* __restrict__ f0_frames,
                                                float* __restrict__ L0,
                                                float* __restrict__ L1) {
    int b = blockIdx.y;
    int chunk = blockIdx.x * 256 + threadIdx.x;     // [0, 16384)
    int g0 = chunk * 16;
    float d = f0_frames[b*NFR + (g0 >> 9)] / 44100.0f;
    float* o = L0 + (size_t)b*LTOT + g0;
    float acc = 0.0f;
    #pragma unroll
    for (int j = 0; j < 16; ++j) { acc = acc + d; o[j] = acc; }
    L1[(size_t)b*NCH + chunk] = acc;
}

// ---------------------------------------------------------------------------
// Scan stage B: finish levels 1..4 for one batch row (16384 elements).
// L2/L3/L4 live in LDS; combine order identical to r13 (top-down, one
// rounded add per level).
// ---------------------------------------------------------------------------
__global__ void __launch_bounds__(1024) k_scan_b(float* __restrict__ L1g) {
    __shared__ float sL2[1024];
    __shared__ float sL3[64];
    __shared__ float sL4[4];
    int b = blockIdx.x, tid = threadIdx.x;
    float* L1 = L1g + (size_t)b*NCH;
    {   // L1 chunk scans (1024 chunks of 16) -> sL2
        float* p = L1 + tid*16;
        float acc = 0.0f;
        #pragma unroll
        for (int j = 0; j < 16; ++j) { acc = acc + p[j]; p[j] = acc; }
        sL2[tid] = acc;
    }
    __syncthreads();
    if (tid < 64) {
        float acc = 0.0f;
        #pragma unroll
        for (int j = 0; j < 16; ++j) { acc = acc + sL2[tid*16+j]; sL2[tid*16+j] = acc; }
        sL3[tid] = acc;
    }
    __syncthreads();
    if (tid < 4) {
        float acc = 0.0f;
        #pragma unroll
        for (int j = 0; j < 16; ++j) { acc = acc + sL3[tid*16+j]; sL3[tid*16+j] = acc; }
        sL4[tid] = acc;
    }
    __syncthreads();
    if (tid == 0) {
        float acc = 0.0f;
        #pragma unroll
        for (int j = 0; j < 4; ++j) { acc = acc + sL4[j]; sL4[j] = acc; }
    }
    __syncthreads();
    if (tid >= 16 && tid < 64) sL3[tid] = sL3[tid] + sL4[tid/16 - 1];
    __syncthreads();
    if (tid >= 16) sL2[tid] = sL2[tid] + sL3[tid/16 - 1];
    __syncthreads();
    for (int i = tid; i < NCH; i += 1024)
        if (i >= 16) L1[i] = L1[i] + sL2[i/16 - 1];
}

// ---------------------------------------------------------------------------
// Source: fuse the final combine (c = L0[g] + L1carry, one rounded add — the
// r13 level-0 combine) with the f32 Dirichlet eval (numpy op order).
// ---------------------------------------------------------------------------
__global__ void __launch_bounds__(256) k_source(const float* __restrict__ f0_frames,
                                                const float* __restrict__ L0,
                                                const float* __restrict__ L1,
                                                float* __restrict__ hs) {
    int F = blockIdx.x, b = blockIdx.y;
    int tid = threadIdx.x;
    float f0 = f0_frames[b*NFR + F];
    float af = rintf(44100.0f / fmaxf(f0, 20.0f) * 0.5f) * 2.0f + 1.0f;
    const float PIF = 3.14159274101257324f;   // float32(np.pi)
    for (int i = tid; i < BLKS; i += 256) {
        int g = F*BLKS + i;
        float c = L0[(size_t)b*LTOT + g];
        if (g >= 16) c = c + L1[(size_t)b*NCH + (g >> 4) - 1];
        float x = c - floorf(c);
        float pix = PIF * x;
        float v;
        if (pix < 1e-8f) v = 1.0f;
        else             v = sinf(af * pix) / (af * sinf(pix));
        hs[(size_t)b*LTOT + g] = v;
    }
}

// ---------------------------------------------------------------------------
// Stage-1 FIR: mix[t] = sum_k hks[fr(u)][k]*hs[u] + nk[fr(u)][k]*nz[u],
// u = j + k, k in [0,512), fr(u) = F-1 + (u>>9).
// R=4 outputs/thread, sliding windows, skewed LDS sources.
// ---------------------------------------------------------------------------
__global__ void __launch_bounds__(128) k_mix(const float* __restrict__ hs,
                                             const float* __restrict__ sn,
                                             const float* __restrict__ hks,
                                             const float* __restrict__ nk,
                                             float* __restrict__ mixg) {
    __shared__ float sHs[SK(1024) + 4];
    __shared__ float sNz[SK(1024) + 4];
    int F = blockIdx.x, b = blockIdx.y;
    int tid = threadIdx.x;
    int s0 = (F - 1) * BLKS;
    for (int i = tid; i < 1024; i += 128) {
        int s = s0 + i;
        float hv = 0.0f, nv = 0.0f;
        if (s >= 0) {
            hv = hs[(size_t)b*LTOT + s];
            nv = sn[s % SN_LEN] * 0.3162f;
        }
        sHs[SK(i)] = hv; sNz[SK(i)] = nv;
    }
    __syncthreads();
    int j0 = tid * 4;
    const float* hksb = hks + (size_t)b*NFR*W4;
    const float* nkb  = nk  + (size_t)b*NFR*W4;
    float a0=0.f,a1=0.f,a2=0.f,a3=0.f;
    float h0=0.f,h1=0.f,h2=0.f,h3=0.f;
    float n0=0.f,n1=0.f,n2=0.f,n3=0.f;
    #pragma unroll 4
    for (int i = 0; i < 512 + 3; ++i) {
        int u = j0 + i;                       // source pos in window [0,1024)
        int rowg = F - 1 + (u >> 9);          // global source frame
        bool rowok = (rowg >= 0);
        const float* hr = hksb + (size_t)rowg * W4;
        const float* nr = nkb  + (size_t)rowg * W4;
        h3=h2; h2=h1; h1=h0;  n3=n2; n2=n1; n1=n0;
        bool f0ok = (i < 512) && rowok;
        h0 = f0ok ? hr[i] : 0.0f;
        n0 = f0ok ? nr[i] : 0.0f;
        int um = u & 511;
        if (um < 3) {                         // crossed row boundary: reload
            int k1 = i-1, k2 = i-2, k3 = i-3;
            if (um < 1) { bool g1 = (k1>=0 && k1<512 && rowok);
                          h1 = g1 ? hr[k1] : 0.0f; n1 = g1 ? nr[k1] : 0.0f; }
            if (um < 2) { bool g2 = (k2>=0 && k2<512 && rowok);
                          h2 = g2 ? hr[k2] : 0.0f; n2 = g2 ? nr[k2] : 0.0f; }
            { bool g3 = (k3>=0 && k3<512 && rowok);
              h3 = g3 ? hr[k3] : 0.0f; n3 = g3 ? nr[k3] : 0.0f; }
        }
        float hv = sHs[SK(u)];
        float nv = sNz[SK(u)];
        a0 += h0*hv; a0 += n0*nv;
        a1 += h1*hv; a1 += n1*nv;
        a2 += h2*hv; a2 += n2*nv;
        a3 += h3*hv; a3 += n3*nv;
    }
    float* o = mixg + (size_t)b*LTOT + F*BLKS + j0;
    o[0]=a0; o[1]=a1; o[2]=a2; o[3]=a3;
}

// ---------------------------------------------------------------------------
// Stage-2 FIR: out[t] = clip( sum_k hk[fr(u)][k]*mix[u] ), u = j + k,
// k in [0,2048), fr(u) = F-4 + (u>>9). Same R=4 sliding-window structure.
// ---------------------------------------------------------------------------
__global__ void __launch_bounds__(128) k_out(const float* __restrict__ mixg,
                                             const float* __restrict__ hk,
                                             float* __restrict__ outp) {
    __shared__ float sMix[SK(2560) + 4];
    int F = blockIdx.x, b = blockIdx.y;
    int tid = threadIdx.x;
    int s0 = (F - 4) * BLKS;
    for (int i = tid; i < 2560; i += 128) {
        int s = s0 + i;
        sMix[SK(i)] = (s >= 0) ? mixg[(size_t)b*LTOT + s] : 0.0f;
    }
    __syncthreads();
    int j0 = tid * 4;
    const float* hkb = hk + (size_t)b*NFR*WL;
    float a0=0.f,a1=0.f,a2=0.f,a3=0.f;
    float w0=0.f,w1=0.f,w2=0.f,w3=0.f;
    #pragma unroll 4
    for (int i = 0; i < 2048 + 3; ++i) {
        int u = j0 + i;                       // source pos in window [0,2560)
        int rowg = F - 4 + (u >> 9);
        bool rowok = (rowg >= 0);
        const float* hr = hkb + (size_t)rowg * WL;
        w3=w2; w2=w1; w1=w0;
        w0 = ((i < 2048) && rowok) ? hr[i] : 0.0f;
        int um = u & 511;
        if (um < 3) {                         // row boundary: reload window
            int k1 = i-1, k2 = i-2, k3 = i-3;
            if (um < 1) w1 = (k1>=0 && k1<2048 && rowok) ? hr[k1] : 0.0f;
            if (um < 2) w2 = (k2>=0 && k2<2048 && rowok) ? hr[k2] : 0.0f;
            w3 = (k3>=0 && k3<2048 && rowok) ? hr[k3] : 0.0f;
        }
        float mv = sMix[SK(u)];
        a0 += w0*mv; a1 += w1*mv; a2 += w2*mv; a3 += w3*mv;
    }
    float* o = outp + (size_t)b*LTOT + F*BLKS + j0;
    o[0] = fminf(fmaxf(a0, -1.0f), 1.0f);
    o[1] = fminf(fmaxf(a1, -1.0f), 1.0f);
    o[2] = fminf(fmaxf(a2, -1.0f), 1.0f);
    o[3] = fminf(fmaxf(a3, -1.0f), 1.0f);
}

// ---------------------------------------------------------------------------
extern "C" void kernel_launch(void* const* d_in, const int* in_sizes, int n_in,
                              void* d_out, int out_size, void* d_ws, size_t ws_size,
                              hipStream_t stream) {
    const float* f0  = (const float*)d_in[0];   // (B,NF,1)
    const float* hk  = (const float*)d_in[1];   // (B,NF,2048)
    const float* hks = (const float*)d_in[2];   // (B,NF,512)
    const float* nk  = (const float*)d_in[3];   // (B,NF,512)
    const float* sn  = (const float*)d_in[4];   // (260096,)
    float* outp = (float*)d_out;                // (B,L) f32

    float* ws   = (float*)d_ws;
    float* L0   = ws;                                   // NB*L      = 4 MB
    float* L1   = L0 + (size_t)NB*LTOT;                 // NB*16384  = 256 KB
    float* hsb  = L1 + (size_t)NB*NCH;                  // NB*L      = 4 MB
    float* mixg = hsb + (size_t)NB*LTOT;                // NB*L      = 4 MB
    // ws bytes ~= 12.3 MB

    hipLaunchKernelGGL(k_scan_a, dim3(64, NB),  dim3(256),  0, stream, f0, L0, L1);
    hipLaunchKernelGGL(k_scan_b, dim3(NB),      dim3(1024), 0, stream, L1);
    hipLaunchKernelGGL(k_source, dim3(NFR, NB), dim3(256),  0, stream, f0, L0, L1, hsb);
    hipLaunchKernelGGL(k_mix,    dim3(NFR, NB), dim3(128),  0, stream, hsb, sn, hks, nk, mixg);
    hipLaunchKernelGGL(k_out,    dim3(NFR, NB), dim3(128),  0, stream, mixg, hk, outp);
}

// Round 15
// 209.289 us; speedup vs baseline: 3.0507x; 3.0507x over previous
//
#include <hip/hip_runtime.h>

// FirNeXtV2 DDSP synth. Numerics certified r13 (absmax 0.0078125): chunked
// f32 cumsum (base 16), f32 Dirichlet eval (numpy op order), f32 convs with
// reassociation tolerance (r13==r14 absmax). Perf v3: 2-D register-tiled
// FIRs (4 outputs x 4 taps per thread, sliding f4 coefficient window,
// wave-uniform b128 source broadcast), fixed-row q-segments, zero-padded
// LDS aprons for the triangular segments (bitwise-exact +0 taps).

#define BLKS  512
#define WL    2048
#define W4    512
#define NB    4
#define NFR   512
#define LTOT  (NFR*BLKS)     // 262144
#define NCH   (LTOT/16)      // 16384
#define SN_LEN 260096        // WL*127

typedef float f4 __attribute__((ext_vector_type(4)));

// 16 FMAs for a 4x4 (output x tap) tile. Per-accumulator tap order is
// ascending m (matches r13's per-output sequential sum).
static __device__ __forceinline__ void step16(const f4 hA, const f4 hB, const f4 x,
                                              float& a0, float& a1, float& a2, float& a3) {
    a0 += hB.x*x.x; a0 += hB.y*x.y; a0 += hB.z*x.z; a0 += hB.w*x.w;
    a1 += hA.w*x.x; a1 += hB.x*x.y; a1 += hB.y*x.z; a1 += hB.z*x.w;
    a2 += hA.z*x.x; a2 += hA.w*x.y; a2 += hB.x*x.z; a2 += hB.y*x.w;
    a3 += hA.y*x.x; a3 += hA.z*x.y; a3 += hA.w*x.z; a3 += hB.x*x.w;
}

// One 512-tap segment: out[j0+r] += sum_m P[c0 - r + m] * S[m]
static __device__ __forceinline__ void seg4(const float* __restrict__ P, int c0,
                                            const float* __restrict__ S,
                                            float& a0, float& a1, float& a2, float& a3) {
    f4 hA = *(const f4*)(P + c0 - 4);
    #pragma unroll 4
    for (int m0 = 0; m0 < 512; m0 += 4) {
        f4 hB = *(const f4*)(P + c0 + m0);
        f4 x  = *(const f4*)(S + m0);
        step16(hA, hB, x, a0, a1, a2, a3);
        hA = hB;
    }
}

// Paired segment (harmonic + noise), preserving r13's per-tap pairing
// acc += h*s + n*z (single expression, same contraction shape).
static __device__ __forceinline__ void seg4x2(const float* __restrict__ Ph,
                                              const float* __restrict__ Pn, int c0,
                                              const float* __restrict__ Sh,
                                              const float* __restrict__ Sn,
                                              float& a0, float& a1, float& a2, float& a3) {
    f4 hA = *(const f4*)(Ph + c0 - 4);
    f4 nA = *(const f4*)(Pn + c0 - 4);
    #pragma unroll 2
    for (int m0 = 0; m0 < 512; m0 += 4) {
        f4 hB = *(const f4*)(Ph + c0 + m0);
        f4 nB = *(const f4*)(Pn + c0 + m0);
        f4 xh = *(const f4*)(Sh + m0);
        f4 xn = *(const f4*)(Sn + m0);
        a0 += hB.x*xh.x + nB.x*xn.x;  a0 += hB.y*xh.y + nB.y*xn.y;
        a0 += hB.z*xh.z + nB.z*xn.z;  a0 += hB.w*xh.w + nB.w*xn.w;
        a1 += hA.w*xh.x + nA.w*xn.x;  a1 += hB.x*xh.y + nB.x*xn.y;
        a1 += hB.y*xh.z + nB.y*xn.z;  a1 += hB.z*xh.w + nB.z*xn.w;
        a2 += hA.z*xh.x + nA.z*xn.x;  a2 += hA.w*xh.y + nA.w*xn.y;
        a2 += hB.x*xh.z + nB.x*xn.z;  a2 += hB.y*xh.w + nB.y*xn.w;
        a3 += hA.y*xh.x + nA.y*xn.x;  a3 += hA.z*xh.y + nA.z*xn.y;
        a3 += hA.w*xh.z + nA.w*xn.z;  a3 += hB.x*xh.w + nB.x*xn.w;
        hA = hB; nA = nB;
    }
}

// ---------------------------------------------------------------------------
// Scan stage A (r14, certified): level-0 chunk scans, d recomputed from f0.
// ---------------------------------------------------------------------------
__global__ void __launch_bounds__(256) k_scan_a(const float* __restrict__ f0_frames,
                                                float* __restrict__ L0,
                                                float* __restrict__ L1) {
    int b = blockIdx.y;
    int chunk = blockIdx.x * 256 + threadIdx.x;     // [0, 16384)
    int g0 = chunk * 16;
    float d = f0_frames[b*NFR + (g0 >> 9)] / 44100.0f;
    float* o = L0 + (size_t)b*LTOT + g0;
    float acc = 0.0f;
    #pragma unroll
    for (int j = 0; j < 16; ++j) { acc = acc + d; o[j] = acc; }
    L1[(size_t)b*NCH + chunk] = acc;
}

// ---------------------------------------------------------------------------
// Scan stage B (r14, certified): levels 1..4 + top-down combine for one row.
// ---------------------------------------------------------------------------
__global__ void __launch_bounds__(1024) k_scan_b(float* __restrict__ L1g) {
    __shared__ float sL2[1024];
    __shared__ float sL3[64];
    __shared__ float sL4[4];
    int b = blockIdx.x, tid = threadIdx.x;
    float* L1 = L1g + (size_t)b*NCH;
    {
        float* p = L1 + tid*16;
        float acc = 0.0f;
        #pragma unroll
        for (int j = 0; j < 16; ++j) { acc = acc + p[j]; p[j] = acc; }
        sL2[tid] = acc;
    }
    __syncthreads();
    if (tid < 64) {
        float acc = 0.0f;
        #pragma unroll
        for (int j = 0; j < 16; ++j) { acc = acc + sL2[tid*16+j]; sL2[tid*16+j] = acc; }
        sL3[tid] = acc;
    }
    __syncthreads();
    if (tid < 4) {
        float acc = 0.0f;
        #pragma unroll
        for (int j = 0; j < 16; ++j) { acc = acc + sL3[tid*16+j]; sL3[tid*16+j] = acc; }
        sL4[tid] = acc;
    }
    __syncthreads();
    if (tid == 0) {
        float acc = 0.0f;
        #pragma unroll
        for (int j = 0; j < 4; ++j) { acc = acc + sL4[j]; sL4[j] = acc; }
    }
    __syncthreads();
    if (tid >= 16 && tid < 64) sL3[tid] = sL3[tid] + sL4[tid/16 - 1];
    __syncthreads();
    if (tid >= 16) sL2[tid] = sL2[tid] + sL3[tid/16 - 1];
    __syncthreads();
    for (int i = tid; i < NCH; i += 1024)
        if (i >= 16) L1[i] = L1[i] + sL2[i/16 - 1];
}

// ---------------------------------------------------------------------------
// Source (r14, certified): fused level-0 combine + f32 Dirichlet eval.
// ---------------------------------------------------------------------------
__global__ void __launch_bounds__(256) k_source(const float* __restrict__ f0_frames,
                                                const float* __restrict__ L0,
                                                const float* __restrict__ L1,
                                                float* __restrict__ hs) {
    int F = blockIdx.x, b = blockIdx.y;
    int tid = threadIdx.x;
    float f0 = f0_frames[b*NFR + F];
    float af = rintf(44100.0f / fmaxf(f0, 20.0f) * 0.5f) * 2.0f + 1.0f;
    const float PIF = 3.14159274101257324f;
    for (int i = tid; i < BLKS; i += 256) {
        int g = F*BLKS + i;
        float c = L0[(size_t)b*LTOT + g];
        if (g >= 16) c = c + L1[(size_t)b*NCH + (g >> 4) - 1];
        float x = c - floorf(c);
        float pix = PIF * x;
        float v;
        if (pix < 1e-8f) v = 1.0f;
        else             v = sinf(af * pix) / (af * sinf(pix));
        hs[(size_t)b*LTOT + g] = v;
    }
}

// ---------------------------------------------------------------------------
// Stage-1 FIR, tiled. Segments (r13 order: frame F, then F-1), coefficients
// zero-padded in LDS so both triangular segments run as full 512-tap loops.
// ---------------------------------------------------------------------------
__global__ void __launch_bounds__(128) k_mix(const float* __restrict__ hs,
                                             const float* __restrict__ sn,
                                             const float* __restrict__ hks,
                                             const float* __restrict__ nk,
                                             float* __restrict__ mixg) {
    __shared__ float sH[1024], sN[1024];
    __shared__ float Hh1[1024], Hn1[1024];   // row F, zeros in [512,1024)
    __shared__ float Hh0[1024], Hn0[1024];   // zeros in [0,512), row F-1 above
    int F = blockIdx.x, b = blockIdx.y, tid = threadIdx.x;
    int s0 = (F - 1) * BLKS;
    for (int i = tid; i < 1024; i += 128) {
        int s = s0 + i;
        float hv = 0.0f, nv = 0.0f;
        if (s >= 0) { hv = hs[(size_t)b*LTOT + s]; nv = sn[s % SN_LEN] * 0.3162f; }
        sH[i] = hv; sN[i] = nv;
    }
    const float* kh = hks + ((size_t)b*NFR + F)*W4;
    const float* kn = nk  + ((size_t)b*NFR + F)*W4;
    for (int i = tid; i < 1024; i += 128) {
        Hh1[i] = (i < 512) ? kh[i] : 0.0f;
        Hn1[i] = (i < 512) ? kn[i] : 0.0f;
        float hp = 0.0f, np_ = 0.0f;
        if (i >= 512 && F >= 1) { hp = kh[i - 1024]; np_ = kn[i - 1024]; } // row F-1
        Hh0[i] = hp; Hn0[i] = np_;
    }
    __syncthreads();
    int j0 = tid * 4;
    float a0=0.f, a1=0.f, a2=0.f, a3=0.f;
    // frame F:  out[j] += kh[512-j+m]*sH[512+m] + kn[..]*sN[512+m]  (pad >=512)
    seg4x2(Hh1, Hn1, 512 - j0, sH + 512, sN + 512, a0, a1, a2, a3);
    // frame F-1: out[j] += khP[m-j]*sH[m] + knP[..]*sN[m]           (pad < 0)
    seg4x2(Hh0 + 512, Hn0 + 512, -j0, sH, sN, a0, a1, a2, a3);
    f4 r; r.x=a0; r.y=a1; r.z=a2; r.w=a3;
    *(f4*)(mixg + (size_t)b*LTOT + F*BLKS + j0) = r;
}

// ---------------------------------------------------------------------------
// Stage-2 FIR, tiled. q=1..3 full segments stream coefficients from global
// (coalesced f4, L1-resident); q=4 / q=0 use zero-padded LDS rows.
// Segment order = r13: q1,q2,q3, then q4 (row F), then q0 (row F-4).
// ---------------------------------------------------------------------------
__global__ void __launch_bounds__(128) k_out(const float* __restrict__ mixg,
                                             const float* __restrict__ hk,
                                             float* __restrict__ outp) {
    __shared__ float sM[2560];
    __shared__ float H4[1024];     // hk row F [1536..2048), zeros above
    __shared__ float H0[1024];     // zeros below, hk row F-4 [0..512) above
    int F = blockIdx.x, b = blockIdx.y, tid = threadIdx.x;
    int s0 = (F - 4) * BLKS;
    const float* mb = mixg + (size_t)b*LTOT;
    for (int i = tid; i < 2560; i += 128) {
        int s = s0 + i;
        sM[i] = (s >= 0) ? mb[s] : 0.0f;
    }
    const float* rF = hk + ((size_t)b*NFR + F)*WL;
    for (int i = tid; i < 1024; i += 128)
        H4[i] = (i < 512) ? rF[1536 + i] : 0.0f;
    for (int i = tid; i < 1024; i += 128) {
        float v = 0.0f;
        if (i >= 512 && F >= 4) v = hk[((size_t)b*NFR + F - 4)*WL + (i - 512)];
        H0[i] = v;
    }
    __syncthreads();
    int j0 = tid * 4;
    float a0=0.f, a1=0.f, a2=0.f, a3=0.f;
    #pragma unroll 1
    for (int q = 1; q <= 3; ++q) {
        int fs = F - 4 + q;
        if (fs < 0) continue;                       // uniform per block
        const float* P = hk + ((size_t)b*NFR + fs)*WL;
        seg4(P, 512*q - j0, sM + 512*q, a0, a1, a2, a3);
    }
    seg4(H4, 512 - j0, sM + 2048, a0, a1, a2, a3);  // row F (m < j taps)
    seg4(H0 + 512, -j0, sM, a0, a1, a2, a3);        // row F-4 (m >= j taps)
    f4 r;
    r.x = fminf(fmaxf(a0, -1.0f), 1.0f);
    r.y = fminf(fmaxf(a1, -1.0f), 1.0f);
    r.z = fminf(fmaxf(a2, -1.0f), 1.0f);
    r.w = fminf(fmaxf(a3, -1.0f), 1.0f);
    *(f4*)(outp + (size_t)b*LTOT + F*BLKS + j0) = r;
}

// ---------------------------------------------------------------------------
extern "C" void kernel_launch(void* const* d_in, const int* in_sizes, int n_in,
                              void* d_out, int out_size, void* d_ws, size_t ws_size,
                              hipStream_t stream) {
    const float* f0  = (const float*)d_in[0];   // (B,NF,1)
    const float* hk  = (const float*)d_in[1];   // (B,NF,2048)
    const float* hks = (const float*)d_in[2];   // (B,NF,512)
    const float* nk  = (const float*)d_in[3];   // (B,NF,512)
    const float* sn  = (const float*)d_in[4];   // (260096,)
    float* outp = (float*)d_out;                // (B,L) f32

    float* ws   = (float*)d_ws;
    float* L0   = ws;                                   // NB*L     = 4 MB
    float* L1   = L0 + (size_t)NB*LTOT;                 // NB*16384 = 256 KB
    float* hsb  = L1 + (size_t)NB*NCH;                  // NB*L     = 4 MB
    float* mixg = hsb + (size_t)NB*LTOT;                // NB*L     = 4 MB

    hipLaunchKernelGGL(k_scan_a, dim3(64, NB),  dim3(256),  0, stream, f0, L0, L1);
    hipLaunchKernelGGL(k_scan_b, dim3(NB),      dim3(1024), 0, stream, L1);
    hipLaunchKernelGGL(k_source, dim3(NFR, NB), dim3(256),  0, stream, f0, L0, L1, hsb);
    hipLaunchKernelGGL(k_mix,    dim3(NFR, NB), dim3(128),  0, stream, hsb, sn, hks, nk, mixg);
    hipLaunchKernelGGL(k_out,    dim3(NFR, NB), dim3(128),  0, stream, mixg, hk, outp);
}

// Round 16
// 176.580 us; speedup vs baseline: 3.6158x; 1.1852x over previous
//
#include <hip/hip_runtime.h>

// FirNeXtV2 DDSP synth. Numerics certified r13/r15 (absmax 0.0078125):
// chunked f32 cumsum (base 16), f32 Dirichlet eval, f32 convs (reassociation
// within tolerance). Perf v4: 64-thread blocks, R=8 outputs/thread, LDS
// zero-padded coefficient windows (uniform c0 = 512-j0 for ALL segments),
// wave-uniform global f4 source loads, inline noise scaling.

#define BLKS  512
#define WL    2048
#define W4    512
#define NB    4
#define NFR   512
#define LTOT  (NFR*BLKS)     // 262144
#define NCH   (LTOT/16)      // 16384
#define SN_LEN 260096        // WL*127 (multiple of 512)

typedef float f4 __attribute__((ext_vector_type(4)));

// 8 outputs x 4 taps: window W[w] = P[c0+m0-8+w]; coef(r,e) = W[8-r+e].
#define ROW1(r, W0,W1,W2,W3) \
    a##r += W0*x.x; a##r += W1*x.y; a##r += W2*x.z; a##r += W3*x.w;

static __device__ __forceinline__ void seg8(const float* __restrict__ P, int c0,
                                            const float* __restrict__ S,
                                            float&a0,float&a1,float&a2,float&a3,
                                            float&a4,float&a5,float&a6,float&a7) {
    f4 A = *(const f4*)(P + c0 - 8);
    f4 B = *(const f4*)(P + c0 - 4);
    #pragma unroll 4
    for (int m0 = 0; m0 < 512; m0 += 4) {
        f4 C = *(const f4*)(P + c0 + m0);
        f4 x = *(const f4*)(S + m0);
        ROW1(0, C.x,C.y,C.z,C.w)
        ROW1(1, B.w,C.x,C.y,C.z)
        ROW1(2, B.z,B.w,C.x,C.y)
        ROW1(3, B.y,B.z,B.w,C.x)
        ROW1(4, B.x,B.y,B.z,B.w)
        ROW1(5, A.w,B.x,B.y,B.z)
        ROW1(6, A.z,A.w,B.x,B.y)
        ROW1(7, A.y,A.z,A.w,B.x)
        A = B; B = C;
    }
}

// Paired (harmonic + noise) segment; h-tap then n-tap per (r,e), ascending m.
#define ROW2(r, H0,H1,H2,H3, N0,N1,N2,N3) \
    a##r += H0*xh.x; a##r += N0*xn.x;  a##r += H1*xh.y; a##r += N1*xn.y; \
    a##r += H2*xh.z; a##r += N2*xn.z;  a##r += H3*xh.w; a##r += N3*xn.w;

static __device__ __forceinline__ void segmix(const float* __restrict__ Ph,
                                              const float* __restrict__ Pn, int c0,
                                              const float* __restrict__ Sh,
                                              const float* __restrict__ Sn,
                                              float&a0,float&a1,float&a2,float&a3,
                                              float&a4,float&a5,float&a6,float&a7) {
    f4 Ah = *(const f4*)(Ph + c0 - 8);
    f4 Bh = *(const f4*)(Ph + c0 - 4);
    f4 An = *(const f4*)(Pn + c0 - 8);
    f4 Bn = *(const f4*)(Pn + c0 - 4);
    #pragma unroll 2
    for (int m0 = 0; m0 < 512; m0 += 4) {
        f4 Ch = *(const f4*)(Ph + c0 + m0);
        f4 Cn = *(const f4*)(Pn + c0 + m0);
        f4 xh = *(const f4*)(Sh + m0);
        f4 xr = *(const f4*)(Sn + m0);
        f4 xn; xn.x = xr.x*0.3162f; xn.y = xr.y*0.3162f;
               xn.z = xr.z*0.3162f; xn.w = xr.w*0.3162f;
        ROW2(0, Ch.x,Ch.y,Ch.z,Ch.w, Cn.x,Cn.y,Cn.z,Cn.w)
        ROW2(1, Bh.w,Ch.x,Ch.y,Ch.z, Bn.w,Cn.x,Cn.y,Cn.z)
        ROW2(2, Bh.z,Bh.w,Ch.x,Ch.y, Bn.z,Bn.w,Cn.x,Cn.y)
        ROW2(3, Bh.y,Bh.z,Bh.w,Ch.x, Bn.y,Bn.z,Bn.w,Cn.x)
        ROW2(4, Bh.x,Bh.y,Bh.z,Bh.w, Bn.x,Bn.y,Bn.z,Bn.w)
        ROW2(5, Ah.w,Bh.x,Bh.y,Bh.z, An.w,Bn.x,Bn.y,Bn.z)
        ROW2(6, Ah.z,Ah.w,Bh.x,Bh.y, An.z,An.w,Bn.x,Bn.y)
        ROW2(7, Ah.y,Ah.z,Ah.w,Bh.x, An.y,An.z,An.w,Bn.x)
        Ah = Bh; Bh = Ch; An = Bn; Bn = Cn;
    }
}

// ---------------------------------------------------------------------------
__global__ void __launch_bounds__(256) k_scan_a(const float* __restrict__ f0_frames,
                                                float* __restrict__ L0,
                                                float* __restrict__ L1) {
    int b = blockIdx.y;
    int chunk = blockIdx.x * 256 + threadIdx.x;
    int g0 = chunk * 16;
    float d = f0_frames[b*NFR + (g0 >> 9)] / 44100.0f;
    float* o = L0 + (size_t)b*LTOT + g0;
    float acc = 0.0f;
    #pragma unroll
    for (int j = 0; j < 16; ++j) { acc = acc + d; o[j] = acc; }
    L1[(size_t)b*NCH + chunk] = acc;
}

__global__ void __launch_bounds__(1024) k_scan_b(float* __restrict__ L1g) {
    __shared__ float sL2[1024];
    __shared__ float sL3[64];
    __shared__ float sL4[4];
    int b = blockIdx.x, tid = threadIdx.x;
    float* L1 = L1g + (size_t)b*NCH;
    {
        float* p = L1 + tid*16;
        float acc = 0.0f;
        #pragma unroll
        for (int j = 0; j < 16; ++j) { acc = acc + p[j]; p[j] = acc; }
        sL2[tid] = acc;
    }
    __syncthreads();
    if (tid < 64) {
        float acc = 0.0f;
        #pragma unroll
        for (int j = 0; j < 16; ++j) { acc = acc + sL2[tid*16+j]; sL2[tid*16+j] = acc; }
        sL3[tid] = acc;
    }
    __syncthreads();
    if (tid < 4) {
        float acc = 0.0f;
        #pragma unroll
        for (int j = 0; j < 16; ++j) { acc = acc + sL3[tid*16+j]; sL3[tid*16+j] = acc; }
        sL4[tid] = acc;
    }
    __syncthreads();
    if (tid == 0) {
        float acc = 0.0f;
        #pragma unroll
        for (int j = 0; j < 4; ++j) { acc = acc + sL4[j]; sL4[j] = acc; }
    }
    __syncthreads();
    if (tid >= 16 && tid < 64) sL3[tid] = sL3[tid] + sL4[tid/16 - 1];
    __syncthreads();
    if (tid >= 16) sL2[tid] = sL2[tid] + sL3[tid/16 - 1];
    __syncthreads();
    for (int i = tid; i < NCH; i += 1024)
        if (i >= 16) L1[i] = L1[i] + sL2[i/16 - 1];
}

__global__ void __launch_bounds__(256) k_source(const float* __restrict__ f0_frames,
                                                const float* __restrict__ L0,
                                                const float* __restrict__ L1,
                                                float* __restrict__ hs) {
    int F = blockIdx.x, b = blockIdx.y;
    int tid = threadIdx.x;
    float f0 = f0_frames[b*NFR + F];
    float af = rintf(44100.0f / fmaxf(f0, 20.0f) * 0.5f) * 2.0f + 1.0f;
    const float PIF = 3.14159274101257324f;
    for (int i = tid; i < BLKS; i += 256) {
        int g = F*BLKS + i;
        float c = L0[(size_t)b*LTOT + g];
        if (g >= 16) c = c + L1[(size_t)b*NCH + (g >> 4) - 1];
        float x = c - floorf(c);
        float pix = PIF * x;
        float v;
        if (pix < 1e-8f) v = 1.0f;
        else             v = sinf(af * pix) / (af * sinf(pix));
        hs[(size_t)b*LTOT + g] = v;
    }
}

// ---------------------------------------------------------------------------
// Stage-1 FIR: 64 threads, R=8. Padded coefficient windows in LDS (16 KB);
// sources (hs, raw noise) via wave-uniform global f4 loads.
// ---------------------------------------------------------------------------
__global__ void __launch_bounds__(64) k_mix(const float* __restrict__ hs,
                                            const float* __restrict__ sn,
                                            const float* __restrict__ hks,
                                            const float* __restrict__ nk,
                                            float* __restrict__ mixg) {
    __shared__ float Wh1[1024], Wn1[1024], Wh0[1024], Wn0[1024];
    int F = blockIdx.x, b = blockIdx.y, tid = threadIdx.x;
    const f4* khF4 = (const f4*)(hks + ((size_t)b*NFR + F)*W4);
    const f4* knF4 = (const f4*)(nk  + ((size_t)b*NFR + F)*W4);
    f4 z; z.x = z.y = z.z = z.w = 0.0f;
    for (int i = tid; i < 256; i += 64) {
        ((f4*)Wh1)[i] = (i < 128) ? khF4[i] : z;
        ((f4*)Wn1)[i] = (i < 128) ? knF4[i] : z;
        ((f4*)Wh0)[i] = (i >= 128 && F >= 1) ? khF4[i - 256] : z;  // row F-1
        ((f4*)Wn0)[i] = (i >= 128 && F >= 1) ? knF4[i - 256] : z;
    }
    __syncthreads();
    int j0 = tid * 8;
    float a0=0,a1=0,a2=0,a3=0,a4=0,a5=0,a6=0,a7=0;
    const float* hsF = hs + (size_t)b*LTOT + (size_t)F*BLKS;
    // frame F segment (taps m<j via zero apron)
    segmix(Wh1, Wn1, 512 - j0, hsF, sn + (F*BLKS) % SN_LEN,
           a0,a1,a2,a3,a4,a5,a6,a7);
    // frame F-1 segment (taps m>=j via zero apron)
    if (F >= 1)
        segmix(Wh0, Wn0, 512 - j0, hsF - BLKS, sn + ((F-1)*BLKS) % SN_LEN,
               a0,a1,a2,a3,a4,a5,a6,a7);
    float* o = mixg + (size_t)b*LTOT + (size_t)F*BLKS + j0;
    f4 r0; r0.x=a0; r0.y=a1; r0.z=a2; r0.w=a3;
    f4 r1; r1.x=a4; r1.y=a5; r1.z=a6; r1.w=a7;
    *(f4*)o = r0; *(f4*)(o + 4) = r1;
}

// ---------------------------------------------------------------------------
// Stage-2 FIR: 64 threads, R=8. Five 1024-float padded windows in LDS (20 KB);
// sources via wave-uniform global f4. Segment order q1,q2,q3,q4,q0 (= r13).
// ---------------------------------------------------------------------------
__global__ void __launch_bounds__(64) k_out(const float* __restrict__ mixg,
                                            const float* __restrict__ hk,
                                            float* __restrict__ outp) {
    __shared__ float Wc[5][1024];
    int F = blockIdx.x, b = blockIdx.y, tid = threadIdx.x;
    f4 z; z.x = z.y = z.z = z.w = 0.0f;
    #pragma unroll
    for (int q = 0; q < 5; ++q) {
        int fs = F - 4 + q;
        const f4* row4 = (const f4*)(hk + ((size_t)b*NFR + fs)*WL);
        f4* Wp = (f4*)Wc[q];
        for (int i = tid; i < 256; i += 64) {
            f4 v = z;
            if (fs >= 0) {
                if (q == 0)      { if (i >= 128) v = row4[i - 128]; }
                else if (q == 4) { if (i < 128)  v = row4[384 + i]; }
                else             v = row4[128*(q-1) + i];
            }
            Wp[i] = v;
        }
    }
    __syncthreads();
    int j0 = tid * 8;
    float a0=0,a1=0,a2=0,a3=0,a4=0,a5=0,a6=0,a7=0;
    const float* mb = mixg + (size_t)b*LTOT;
    #pragma unroll 1
    for (int q = 1; q <= 3; ++q) {
        int fs = F - 4 + q;
        if (fs < 0) continue;                         // uniform per block
        seg8(Wc[q], 512 - j0, mb + (size_t)fs*BLKS, a0,a1,a2,a3,a4,a5,a6,a7);
    }
    seg8(Wc[4], 512 - j0, mb + (size_t)F*BLKS, a0,a1,a2,a3,a4,a5,a6,a7);
    if (F >= 4)
        seg8(Wc[0], 512 - j0, mb + (size_t)(F-4)*BLKS, a0,a1,a2,a3,a4,a5,a6,a7);
    float* o = outp + (size_t)b*LTOT + (size_t)F*BLKS + j0;
    f4 r0, r1;
    r0.x = fminf(fmaxf(a0, -1.0f), 1.0f);
    r0.y = fminf(fmaxf(a1, -1.0f), 1.0f);
    r0.z = fminf(fmaxf(a2, -1.0f), 1.0f);
    r0.w = fminf(fmaxf(a3, -1.0f), 1.0f);
    r1.x = fminf(fmaxf(a4, -1.0f), 1.0f);
    r1.y = fminf(fmaxf(a5, -1.0f), 1.0f);
    r1.z = fminf(fmaxf(a6, -1.0f), 1.0f);
    r1.w = fminf(fmaxf(a7, -1.0f), 1.0f);
    *(f4*)o = r0; *(f4*)(o + 4) = r1;
}

// ---------------------------------------------------------------------------
extern "C" void kernel_launch(void* const* d_in, const int* in_sizes, int n_in,
                              void* d_out, int out_size, void* d_ws, size_t ws_size,
                              hipStream_t stream) {
    const float* f0  = (const float*)d_in[0];   // (B,NF,1)
    const float* hk  = (const float*)d_in[1];   // (B,NF,2048)
    const float* hks = (const float*)d_in[2];   // (B,NF,512)
    const float* nk  = (const float*)d_in[3];   // (B,NF,512)
    const float* sn  = (const float*)d_in[4];   // (260096,)
    float* outp = (float*)d_out;                // (B,L) f32

    float* ws   = (float*)d_ws;
    float* L0   = ws;                                   // NB*L     = 4 MB
    float* L1   = L0 + (size_t)NB*LTOT;                 // NB*16384 = 256 KB
    float* hsb  = L1 + (size_t)NB*NCH;                  // NB*L     = 4 MB
    float* mixg = hsb + (size_t)NB*LTOT;                // NB*L     = 4 MB

    hipLaunchKernelGGL(k_scan_a, dim3(64, NB),  dim3(256),  0, stream, f0, L0, L1);
    hipLaunchKernelGGL(k_scan_b, dim3(NB),      dim3(1024), 0, stream, L1);
    hipLaunchKernelGGL(k_source, dim3(NFR, NB), dim3(256),  0, stream, f0, L0, L1, hsb);
    hipLaunchKernelGGL(k_mix,    dim3(NFR, NB), dim3(64),   0, stream, hsb, sn, hks, nk, mixg);
    hipLaunchKernelGGL(k_out,    dim3(NFR, NB), dim3(64),   0, stream, mixg, hk, outp);
}

// Round 17
// 171.894 us; speedup vs baseline: 3.7144x; 1.0273x over previous
//
#include <hip/hip_runtime.h>

// FirNeXtV2 DDSP synth. Numerics certified r13-r16 (absmax 0.0078125).
// Perf v5: 128-thread blocks, R=4 outputs/thread (lane stride = 1 bank-quad
// -> conflict-free b128), LDS zero-padded coefficient windows, wave-uniform
// global f4 source reads, inline noise scaling.

#define BLKS  512
#define WL    2048
#define W4    512
#define NB    4
#define NFR   512
#define LTOT  (NFR*BLKS)     // 262144
#define NCH   (LTOT/16)      // 16384
#define SN_LEN 260096        // WL*127 (multiple of 512)

typedef float f4 __attribute__((ext_vector_type(4)));

// R=4 x 4 taps; window slides A->B. Per-output taps ascend in m.
static __device__ __forceinline__ void seg4(const float* __restrict__ P, int c0,
                                            const float* __restrict__ S,
                                            float&a0,float&a1,float&a2,float&a3) {
    f4 A = *(const f4*)(P + c0 - 4);
    #pragma unroll 4
    for (int m0 = 0; m0 < 512; m0 += 4) {
        f4 B = *(const f4*)(P + c0 + m0);
        f4 x = *(const f4*)(S + m0);
        a0 += B.x*x.x; a0 += B.y*x.y; a0 += B.z*x.z; a0 += B.w*x.w;
        a1 += A.w*x.x; a1 += B.x*x.y; a1 += B.y*x.z; a1 += B.z*x.w;
        a2 += A.z*x.x; a2 += A.w*x.y; a2 += B.x*x.z; a2 += B.y*x.w;
        a3 += A.y*x.x; a3 += A.z*x.y; a3 += A.w*x.z; a3 += B.x*x.w;
        A = B;
    }
}

// Paired harmonic+noise segment, h-tap then n-tap per element, ascending m.
static __device__ __forceinline__ void segmix(const float* __restrict__ Ph,
                                              const float* __restrict__ Pn, int c0,
                                              const float* __restrict__ Sh,
                                              const float* __restrict__ Sn,
                                              float&a0,float&a1,float&a2,float&a3) {
    f4 Ah = *(const f4*)(Ph + c0 - 4);
    f4 An = *(const f4*)(Pn + c0 - 4);
    #pragma unroll 4
    for (int m0 = 0; m0 < 512; m0 += 4) {
        f4 Bh = *(const f4*)(Ph + c0 + m0);
        f4 Bn = *(const f4*)(Pn + c0 + m0);
        f4 xh = *(const f4*)(Sh + m0);
        f4 xr = *(const f4*)(Sn + m0);
        f4 xn; xn.x = xr.x*0.3162f; xn.y = xr.y*0.3162f;
               xn.z = xr.z*0.3162f; xn.w = xr.w*0.3162f;
        a0 += Bh.x*xh.x; a0 += Bn.x*xn.x;  a0 += Bh.y*xh.y; a0 += Bn.y*xn.y;
        a0 += Bh.z*xh.z; a0 += Bn.z*xn.z;  a0 += Bh.w*xh.w; a0 += Bn.w*xn.w;
        a1 += Ah.w*xh.x; a1 += An.w*xn.x;  a1 += Bh.x*xh.y; a1 += Bn.x*xn.y;
        a1 += Bh.y*xh.z; a1 += Bn.y*xn.z;  a1 += Bh.z*xh.w; a1 += Bn.z*xn.w;
        a2 += Ah.z*xh.x; a2 += An.z*xn.x;  a2 += Ah.w*xh.y; a2 += An.w*xn.y;
        a2 += Bh.x*xh.z; a2 += Bn.x*xn.z;  a2 += Bh.y*xh.w; a2 += Bn.y*xn.w;
        a3 += Ah.y*xh.x; a3 += An.y*xn.x;  a3 += Ah.z*xh.y; a3 += An.z*xn.y;
        a3 += Ah.w*xh.z; a3 += An.w*xn.z;  a3 += Bh.x*xh.w; a3 += Bn.x*xn.w;
        Ah = Bh; An = Bn;
    }
}

// ---------------------------------------------------------------------------
__global__ void __launch_bounds__(256) k_scan_a(const float* __restrict__ f0_frames,
                                                float* __restrict__ L0,
                                                float* __restrict__ L1) {
    int b = blockIdx.y;
    int chunk = blockIdx.x * 256 + threadIdx.x;
    int g0 = chunk * 16;
    float d = f0_frames[b*NFR + (g0 >> 9)] / 44100.0f;
    float* o = L0 + (size_t)b*LTOT + g0;
    float acc = 0.0f;
    #pragma unroll
    for (int j = 0; j < 16; ++j) { acc = acc + d; o[j] = acc; }
    L1[(size_t)b*NCH + chunk] = acc;
}

__global__ void __launch_bounds__(1024) k_scan_b(float* __restrict__ L1g) {
    __shared__ float sL2[1024];
    __shared__ float sL3[64];
    __shared__ float sL4[4];
    int b = blockIdx.x, tid = threadIdx.x;
    float* L1 = L1g + (size_t)b*NCH;
    {
        float* p = L1 + tid*16;
        float acc = 0.0f;
        #pragma unroll
        for (int j = 0; j < 16; ++j) { acc = acc + p[j]; p[j] = acc; }
        sL2[tid] = acc;
    }
    __syncthreads();
    if (tid < 64) {
        float acc = 0.0f;
        #pragma unroll
        for (int j = 0; j < 16; ++j) { acc = acc + sL2[tid*16+j]; sL2[tid*16+j] = acc; }
        sL3[tid] = acc;
    }
    __syncthreads();
    if (tid < 4) {
        float acc = 0.0f;
        #pragma unroll
        for (int j = 0; j < 16; ++j) { acc = acc + sL3[tid*16+j]; sL3[tid*16+j] = acc; }
        sL4[tid] = acc;
    }
    __syncthreads();
    if (tid == 0) {
        float acc = 0.0f;
        #pragma unroll
        for (int j = 0; j < 4; ++j) { acc = acc + sL4[j]; sL4[j] = acc; }
    }
    __syncthreads();
    if (tid >= 16 && tid < 64) sL3[tid] = sL3[tid] + sL4[tid/16 - 1];
    __syncthreads();
    if (tid >= 16) sL2[tid] = sL2[tid] + sL3[tid/16 - 1];
    __syncthreads();
    for (int i = tid; i < NCH; i += 1024)
        if (i >= 16) L1[i] = L1[i] + sL2[i/16 - 1];
}

__global__ void __launch_bounds__(256) k_source(const float* __restrict__ f0_frames,
                                                const float* __restrict__ L0,
                                                const float* __restrict__ L1,
                                                float* __restrict__ hs) {
    int F = blockIdx.x, b = blockIdx.y;
    int tid = threadIdx.x;
    float f0 = f0_frames[b*NFR + F];
    float af = rintf(44100.0f / fmaxf(f0, 20.0f) * 0.5f) * 2.0f + 1.0f;
    const float PIF = 3.14159274101257324f;
    for (int i = tid; i < BLKS; i += 256) {
        int g = F*BLKS + i;
        float c = L0[(size_t)b*LTOT + g];
        if (g >= 16) c = c + L1[(size_t)b*NCH + (g >> 4) - 1];
        float x = c - floorf(c);
        float pix = PIF * x;
        float v;
        if (pix < 1e-8f) v = 1.0f;
        else             v = sinf(af * pix) / (af * sinf(pix));
        hs[(size_t)b*LTOT + g] = v;
    }
}

// ---------------------------------------------------------------------------
// Stage-1 FIR: 128 threads, R=4. Padded coeff windows in LDS (16 KB);
// sources (hs, raw noise) via wave-uniform global f4 loads.
// ---------------------------------------------------------------------------
__global__ void __launch_bounds__(128) k_mix(const float* __restrict__ hs,
                                             const float* __restrict__ sn,
                                             const float* __restrict__ hks,
                                             const float* __restrict__ nk,
                                             float* __restrict__ mixg) {
    __shared__ float Wh1[1024], Wn1[1024], Wh0[1024], Wn0[1024];
    int F = blockIdx.x, b = blockIdx.y, tid = threadIdx.x;
    const f4* khF4 = (const f4*)(hks + ((size_t)b*NFR + F)*W4);
    const f4* knF4 = (const f4*)(nk  + ((size_t)b*NFR + F)*W4);
    f4 z; z.x = z.y = z.z = z.w = 0.0f;
    for (int i = tid; i < 256; i += 128) {
        ((f4*)Wh1)[i] = (i < 128) ? khF4[i] : z;
        ((f4*)Wn1)[i] = (i < 128) ? knF4[i] : z;
        ((f4*)Wh0)[i] = (i >= 128 && F >= 1) ? khF4[i - 256] : z;  // row F-1
        ((f4*)Wn0)[i] = (i >= 128 && F >= 1) ? knF4[i - 256] : z;
    }
    __syncthreads();
    int j0 = tid * 4;
    float a0=0,a1=0,a2=0,a3=0;
    const float* hsF = hs + (size_t)b*LTOT + (size_t)F*BLKS;
    segmix(Wh1, Wn1, 512 - j0, hsF, sn + (F*BLKS) % SN_LEN, a0,a1,a2,a3);
    if (F >= 1)
        segmix(Wh0, Wn0, 512 - j0, hsF - BLKS, sn + ((F-1)*BLKS) % SN_LEN,
               a0,a1,a2,a3);
    f4 r; r.x=a0; r.y=a1; r.z=a2; r.w=a3;
    *(f4*)(mixg + (size_t)b*LTOT + (size_t)F*BLKS + j0) = r;
}

// ---------------------------------------------------------------------------
// Stage-2 FIR: 128 threads, R=4. Five padded windows in LDS (20 KB);
// sources via wave-uniform global f4. Segment order q1,q2,q3,q4,q0 (= r13).
// ---------------------------------------------------------------------------
__global__ void __launch_bounds__(128) k_out(const float* __restrict__ mixg,
                                             const float* __restrict__ hk,
                                             float* __restrict__ outp) {
    __shared__ float Wc[5][1024];
    int F = blockIdx.x, b = blockIdx.y, tid = threadIdx.x;
    f4 z; z.x = z.y = z.z = z.w = 0.0f;
    #pragma unroll
    for (int q = 0; q < 5; ++q) {
        int fs = F - 4 + q;
        const f4* row4 = (const f4*)(hk + ((size_t)b*NFR + fs)*WL);
        f4* Wp = (f4*)Wc[q];
        for (int i = tid; i < 256; i += 128) {
            f4 v = z;
            if (fs >= 0) {
                if (q == 0)      { if (i >= 128) v = row4[i - 128]; }
                else if (q == 4) { if (i < 128)  v = row4[384 + i]; }
                else             v = row4[128*(q-1) + i];
            }
            Wp[i] = v;
        }
    }
    __syncthreads();
    int j0 = tid * 4;
    float a0=0,a1=0,a2=0,a3=0;
    const float* mb = mixg + (size_t)b*LTOT;
    #pragma unroll 1
    for (int q = 1; q <= 3; ++q) {
        int fs = F - 4 + q;
        if (fs < 0) continue;                         // uniform per block
        seg4(Wc[q], 512 - j0, mb + (size_t)fs*BLKS, a0,a1,a2,a3);
    }
    seg4(Wc[4], 512 - j0, mb + (size_t)F*BLKS, a0,a1,a2,a3);
    if (F >= 4)
        seg4(Wc[0], 512 - j0, mb + (size_t)(F-4)*BLKS, a0,a1,a2,a3);
    f4 r;
    r.x = fminf(fmaxf(a0, -1.0f), 1.0f);
    r.y = fminf(fmaxf(a1, -1.0f), 1.0f);
    r.z = fminf(fmaxf(a2, -1.0f), 1.0f);
    r.w = fminf(fmaxf(a3, -1.0f), 1.0f);
    *(f4*)(outp + (size_t)b*LTOT + (size_t)F*BLKS + j0) = r;
}

// ---------------------------------------------------------------------------
extern "C" void kernel_launch(void* const* d_in, const int* in_sizes, int n_in,
                              void* d_out, int out_size, void* d_ws, size_t ws_size,
                              hipStream_t stream) {
    const float* f0  = (const float*)d_in[0];   // (B,NF,1)
    const float* hk  = (const float*)d_in[1];   // (B,NF,2048)
    const float* hks = (const float*)d_in[2];   // (B,NF,512)
    const float* nk  = (const float*)d_in[3];   // (B,NF,512)
    const float* sn  = (const float*)d_in[4];   // (260096,)
    float* outp = (float*)d_out;                // (B,L) f32

    float* ws   = (float*)d_ws;
    float* L0   = ws;                                   // NB*L     = 4 MB
    float* L1   = L0 + (size_t)NB*LTOT;                 // NB*16384 = 256 KB
    float* hsb  = L1 + (size_t)NB*NCH;                  // NB*L     = 4 MB
    float* mixg = hsb + (size_t)NB*LTOT;                // NB*L     = 4 MB

    hipLaunchKernelGGL(k_scan_a, dim3(64, NB),  dim3(256),  0, stream, f0, L0, L1);
    hipLaunchKernelGGL(k_scan_b, dim3(NB),      dim3(1024), 0, stream, L1);
    hipLaunchKernelGGL(k_source, dim3(NFR, NB), dim3(256),  0, stream, f0, L0, L1, hsb);
    hipLaunchKernelGGL(k_mix,    dim3(NFR, NB), dim3(128),  0, stream, hsb, sn, hks, nk, mixg);
    hipLaunchKernelGGL(k_out,    dim3(NFR, NB), dim3(128),  0, stream, mixg, hk, outp);
}